// Round 10
// baseline (103.751 us; speedup 1.0000x reference)
//
#include <hip/hip_runtime.h>
#include <math.h>

// Sampler: temperature 0.8, top-k (k=50 input), top-p 0.9, inverse-CDF
// multinomial. B=128 rows, V=128000, fp32 logits -> int32 ids.
//
// R10: two kernels. Scan uses INTERLEAVED slices so all 16 blocks of a row
// march through contiguous memory together (128 coherent streams vs R9's
// 2048 scattered 1KB windows), with 8 named back-to-back float4 loads.
//  K1 scan: B x 16 blocks, 256 thr. Block (row,sl) reads float4 idx
//    sl*256 + tid + j*4096, j=0..7 (covers n4 <= 32768; extra loop + scalar
//    tail for general V). Max-of-4 prefilter, LDS-atomic push of candidates
//    (y >= 11.2 i.e. x >= 14, ~21/block), private 64-entry global segment +
//    plain count store. Zero global atomics (R2), zero fences (R5).
//  K2 select: B x 1024 thr (R9 verbatim): wave-0 shuffle prefix, one wave
//    per segment gather, two-tier filter (x >= 16 when count >= k -> M~88,
//    provably superset of top-k + kth ties), rank sort (x desc, idx asc ==
//    jnp.argsort(-x) stability), R7 block-parallel fp32 tail (reductions/
//    scans/ballots; margins >> rounding). absmax-0 lineage R1-R9.
//  Fallback (segment overflow / total < k): exact kth via binary search on
//  float key bits + rescan. Never fires on this data.

#define SLICES   16
#define SEGCAP   64
#define MSORT    1024

__device__ __forceinline__ unsigned fkey(float y) {
    unsigned b = __float_as_uint(y);
    return (b & 0x80000000u) ? ~b : (b | 0x80000000u);  // y asc -> key asc
}

// block-wide sum over 1024 threads; wpart = shared float[16]; ends synced
__device__ __forceinline__ float block_sum(float v, int tid, float* wpart) {
#pragma unroll
    for (int off = 32; off > 0; off >>= 1) v += __shfl_down(v, off, 64);
    if ((tid & 63) == 0) wpart[tid >> 6] = v;
    __syncthreads();
    if (tid < 64) {
        float s = (tid < 16) ? wpart[tid] : 0.0f;
#pragma unroll
        for (int off = 8; off > 0; off >>= 1) s += __shfl_down(s, off, 64);
        if (tid == 0) wpart[0] = s;
    }
    __syncthreads();
    float s = wpart[0];
    __syncthreads();
    return s;
}

// in-place block inclusive scan of arr[0..n), n <= 1024; ends synced
__device__ __forceinline__ void incl_scan(float* arr, int n, int tid, float* wpart) {
    float v = (tid < n) ? arr[tid] : 0.0f;
#pragma unroll
    for (int off = 1; off < 64; off <<= 1) {
        float o = __shfl_up(v, off, 64);
        if ((tid & 63) >= off) v += o;
    }
    if ((tid & 63) == 63) wpart[tid >> 6] = v;
    __syncthreads();
    if (tid < 64) {
        float w = (tid < 16) ? wpart[tid] : 0.0f;
#pragma unroll
        for (int off = 1; off < 16; off <<= 1) {
            float o = __shfl_up(w, off, 64);
            if (tid >= off) w += o;
        }
        if (tid < 16) wpart[tid] = w;
    }
    __syncthreads();
    const int wv = tid >> 6;
    const float base = (wv > 0) ? wpart[wv - 1] : 0.0f;
    if (tid < n) arr[tid] = v + base;
    __syncthreads();
}

// ---------------- Kernel 1: interleaved full-device candidate scan ----------
__global__ __launch_bounds__(256)
void scan_kernel(const float* __restrict__ logits, int V,
                 int* __restrict__ scnt,
                 float* __restrict__ cy, int* __restrict__ ci)
{
    constexpr float YTH = 11.2f;   // x = 14.0
    __shared__ float lcy[SEGCAP];
    __shared__ int   lci[SEGCAP];
    __shared__ int   lcnt;

    const int tid = threadIdx.x;
    const int row = blockIdx.x / SLICES;
    const int sl  = blockIdx.x % SLICES;
    if (tid == 0) lcnt = 0;
    __syncthreads();

    const float* rowp = logits + (size_t)row * (size_t)V;
    const float4* rp4 = (const float4*)rowp;
    const int n4   = V >> 2;
    const int base = sl * 256 + tid;    // float4 index, stride 4096 per j

#define PUSH4(vv, i4)                                                            \
    {                                                                            \
        float _m = fmaxf(fmaxf((vv).x, (vv).y), fmaxf((vv).z, (vv).w));          \
        if (_m >= YTH) {                                                         \
            if ((vv).x >= YTH) { int _p = atomicAdd(&lcnt, 1);                   \
                if (_p < SEGCAP) { lcy[_p] = (vv).x; lci[_p] = (i4) * 4;     } } \
            if ((vv).y >= YTH) { int _p = atomicAdd(&lcnt, 1);                   \
                if (_p < SEGCAP) { lcy[_p] = (vv).y; lci[_p] = (i4) * 4 + 1; } } \
            if ((vv).z >= YTH) { int _p = atomicAdd(&lcnt, 1);                   \
                if (_p < SEGCAP) { lcy[_p] = (vv).z; lci[_p] = (i4) * 4 + 2; } } \
            if ((vv).w >= YTH) { int _p = atomicAdd(&lcnt, 1);                   \
                if (_p < SEGCAP) { lcy[_p] = (vv).w; lci[_p] = (i4) * 4 + 3; } } \
        }                                                                        \
    }

    // block-uniform: worst lane of this block stays in range for all 8 js?
    if (sl * 256 + 255 + 7 * 4096 < n4) {
        // fast path: 8 unconditional back-to-back loads (full MLP)
        float4 a0 = rp4[base];
        float4 a1 = rp4[base + 4096];
        float4 a2 = rp4[base + 8192];
        float4 a3 = rp4[base + 12288];
        float4 a4 = rp4[base + 16384];
        float4 a5 = rp4[base + 20480];
        float4 a6 = rp4[base + 24576];
        float4 a7 = rp4[base + 28672];
        PUSH4(a0, base);
        PUSH4(a1, base + 4096);
        PUSH4(a2, base + 8192);
        PUSH4(a3, base + 12288);
        PUSH4(a4, base + 16384);
        PUSH4(a5, base + 20480);
        PUSH4(a6, base + 24576);
        PUSH4(a7, base + 28672);
    } else {
        // edge slices: clamped branch-free loads, validity-flagged pushes
        const int nc = n4 - 1;
        int i0 = base,          c0 = min(i0, nc);
        int i1 = base + 4096,   c1 = min(i1, nc);
        int i2 = base + 8192,   c2 = min(i2, nc);
        int i3 = base + 12288,  c3 = min(i3, nc);
        int i4_ = base + 16384, c4 = min(i4_, nc);
        int i5 = base + 20480,  c5 = min(i5, nc);
        int i6 = base + 24576,  c6 = min(i6, nc);
        int i7 = base + 28672,  c7 = min(i7, nc);
        float4 a0 = rp4[c0];
        float4 a1 = rp4[c1];
        float4 a2 = rp4[c2];
        float4 a3 = rp4[c3];
        float4 a4 = rp4[c4];
        float4 a5 = rp4[c5];
        float4 a6 = rp4[c6];
        float4 a7 = rp4[c7];
        if (i0 < n4) PUSH4(a0, i0);
        if (i1 < n4) PUSH4(a1, i1);
        if (i2 < n4) PUSH4(a2, i2);
        if (i3 < n4) PUSH4(a3, i3);
        if (i4_ < n4) PUSH4(a4, i4_);
        if (i5 < n4) PUSH4(a5, i5);
        if (i6 < n4) PUSH4(a6, i6);
        if (i7 < n4) PUSH4(a7, i7);
    }
    // general-V coverage beyond 32768 float4/row (empty for V=128000)
    for (int i = SLICES * 256 * 8 + sl * 256 + tid; i < n4; i += SLICES * 256) {
        float4 a = rp4[i];
        PUSH4(a, i);
    }
    if (sl == SLICES - 1) {   // scalar tail if V % 4 != 0
        for (int i = (n4 << 2) + tid; i < V; i += 256) {
            float y = rowp[i];
            if (y >= YTH) {
                int p = atomicAdd(&lcnt, 1);
                if (p < SEGCAP) { lcy[p] = y; lci[p] = i; }
            }
        }
    }
#undef PUSH4
    __syncthreads();

    const int cnt = lcnt;
    float* cyr = cy + ((size_t)row * SLICES + sl) * SEGCAP;
    int*   cir = ci + ((size_t)row * SLICES + sl) * SEGCAP;
    for (int p = tid; p < min(cnt, SEGCAP); p += 256) {
        cyr[p] = lcy[p];
        cir[p] = lci[p];
    }
    if (tid == 0) scnt[row * SLICES + sl] = cnt;  // cnt > SEGCAP => overflow
}

// ---------------- Kernel 2: per-row selection + sampling --------------------
__global__ __launch_bounds__(1024)
void select_kernel(const float* __restrict__ logits,
                   const float* __restrict__ uvec,
                   const int* __restrict__ topk_p,
                   const int* __restrict__ scnt,
                   const float* __restrict__ cy, const int* __restrict__ ci,
                   int* __restrict__ out, int V)
{
    constexpr float TEMP = 0.8f;
    constexpr float TOPP = 0.9f;
    constexpr float XTH2 = 16.0f;   // two-tier threshold in x-space

    __shared__ float gv[MSORT];
    __shared__ int   gi[MSORT];
    __shared__ float cv[MSORT];
    __shared__ int   cidx[MSORT];
    __shared__ float sq[MSORT];
    __shared__ float wpart[16];
    __shared__ float kth_sh;
    __shared__ int   segoff[SLICES + 1];
    __shared__ int   bad_sh, hi_cnt, cpos, scount, cnt_sh, M_sh, tie_cnt, L_cnt, ans_sh;

    const int tid  = threadIdx.x;
    const int lane = tid & 63;
    const int row  = blockIdx.x;
    const int nth  = blockDim.x;    // 1024
    const int k_in = *topk_p;

    const float* rowp = logits + (size_t)row * (size_t)V;

    if (tid == 0) { hi_cnt = 0; cpos = 0; scount = 0;
                    tie_cnt = 0; L_cnt = 0; ans_sh = V; }
    if (tid < 64) {
        int c = (tid < SLICES) ? scnt[row * SLICES + tid] : 0;
        int bad = (tid < SLICES) && (c > SEGCAP);
        int acc = min(c, SEGCAP);
#pragma unroll
        for (int off = 1; off < SLICES; off <<= 1) {
            int o = __shfl_up(acc, off, 64);
            if (tid >= off) acc += o;
        }
        if (tid < SLICES) segoff[tid + 1] = acc;
        if (tid == 0) segoff[0] = 0;
        unsigned long long bm = __ballot(bad);
        if (tid == 0) bad_sh = (bm != 0ULL);
    }
    __syncthreads();

    const int M_all = segoff[SLICES];
    int M;
    if (!bad_sh && M_all >= k_in && M_all <= MSORT) {
        {
            const int s = tid >> 6;         // one wave per segment
            const int off = segoff[s];
            const int c   = segoff[s + 1] - off;
            if (lane < c) {
                const size_t base = ((size_t)row * SLICES + s) * SEGCAP + lane;
                gv[off + lane] = cy[base] / TEMP;
                gi[off + lane] = ci[base];
            }
        }
        __syncthreads();
        {
            bool pred = (tid < M_all) && (gv[tid] >= XTH2);
            unsigned long long bm = __ballot(pred);
            if (lane == 0 && bm) atomicAdd(&hi_cnt, (int)__popcll(bm));
        }
        __syncthreads();
        const float thr = (hi_cnt >= k_in) ? XTH2 : -1e38f;
        {
            bool pred = (tid < M_all) && (gv[tid] >= thr);
            unsigned long long bm = __ballot(pred);
            if (bm) {
                int fl = (int)__ffsll(bm) - 1;
                int bs = 0;
                if (pred && lane == fl) bs = atomicAdd(&cpos, (int)__popcll(bm));
                bs = __shfl(bs, fl, 64);
                if (pred) {
                    int p = bs + (int)__popcll(bm & ((1ULL << lane) - 1ULL));
                    cv[p] = gv[tid]; cidx[p] = gi[tid];
                }
            }
        }
        __syncthreads();
        M = cpos;
    } else {
        unsigned lo = 0;
        for (int bit = 31; bit >= 0; --bit) {
            unsigned t = lo | (1u << bit);
            int local = 0;
            for (int i = tid; i < V; i += nth) local += (fkey(rowp[i]) >= t);
            if (tid == 0) cnt_sh = 0;
            __syncthreads();
            atomicAdd(&cnt_sh, local);
            __syncthreads();
            if (cnt_sh >= k_in) lo = t;
            __syncthreads();
        }
        for (int i = tid; i < V; i += nth) {
            float y = rowp[i];
            if (fkey(y) >= lo) {
                int p = atomicAdd(&scount, 1);
                if (p < MSORT) { cv[p] = y / TEMP; cidx[p] = i; }
            }
        }
        __syncthreads();
        M = min(scount, MSORT);
    }
    if (tid == 0) M_sh = M;
    __syncthreads();
    M = M_sh;

    const int Mpad = (M + 3) & ~3;
    for (int t = M + tid; t < Mpad; t += nth) { cv[t] = -1e38f; cidx[t] = 0x7fffffff; }
    __syncthreads();

    if (tid < M) {
        const float v = cv[tid]; const int ix = cidx[tid];
        int r = 0;
        for (int j = 0; j < Mpad; j += 4) {
            float v0 = cv[j],     v1 = cv[j + 1];
            float v2 = cv[j + 2], v3 = cv[j + 3];
            int   i0 = cidx[j],     i1 = cidx[j + 1];
            int   i2 = cidx[j + 2], i3 = cidx[j + 3];
            r += (v0 > v || (v0 == v && i0 < ix));
            r += (v1 > v || (v1 == v && i1 < ix));
            r += (v2 > v || (v2 == v && i2 < ix));
            r += (v3 > v || (v3 == v && i3 < ix));
        }
        gv[r] = v; gi[r] = ix;
    }
    __syncthreads();

    const int kk = (M > 0) ? min(max(k_in, 1), M) : 0;
    const float mm = (M > 0) ? gv[0] : 0.0f;
    if (tid < M) cv[tid] = expf(gv[tid] - mm);
    if (tid == 0 && M > 0) kth_sh = gv[kk - 1];
    __syncthreads();

    {
        bool f = (M > 0) && (tid >= kk) && (tid < M) && (gv[tid] == kth_sh);
        unsigned long long bm = __ballot(f);
        if (lane == 0 && bm) atomicAdd(&tie_cnt, (int)__popcll(bm));
    }
    __syncthreads();
    const int Kp = kk + tie_cnt;

    const float sum1 = block_sum((tid < Kp) ? cv[tid] : 0.0f, tid, wpart);

    if (tid < Kp) sq[tid] = cv[tid] / sum1;
    incl_scan(sq, Kp, tid, wpart);
    {
        bool f = (tid >= 1) && (tid < Kp) && (sq[tid - 1] <= TOPP);
        unsigned long long bm = __ballot(f);
        if (lane == 0 && bm) atomicAdd(&L_cnt, (int)__popcll(bm));
    }
    __syncthreads();
    const int L = (M > 0) ? (1 + L_cnt) : 0;

    const float sum2 = block_sum((tid < L) ? cv[tid] : 0.0f, tid, wpart);

    if (tid < L) {
        const int ix = gi[tid];
        int r = 0;
        for (int j = 0; j < L; ++j) r += (gi[j] < ix);
        sq[r] = cv[tid] / sum2;
        cidx[r] = ix;
    }
    __syncthreads();

    incl_scan(sq, L, tid, wpart);
    {
        const float uu = uvec[row];
        bool f = (tid < L) && (sq[tid] > uu) && (tid == 0 || sq[tid - 1] <= uu);
        if (f) ans_sh = cidx[tid];
    }
    __syncthreads();
    if (tid == 0) out[row] = ans_sh;
}

extern "C" void kernel_launch(void* const* d_in, const int* in_sizes, int n_in,
                              void* d_out, int out_size, void* d_ws, size_t ws_size,
                              hipStream_t stream) {
    const float* logits = (const float*)d_in[0];
    const float* u      = (const float*)d_in[1];
    const int*   topk   = (const int*)d_in[2];
    int*         out    = (int*)d_out;

    const int B = out_size;              // 128 rows
    const int V = in_sizes[0] / B;       // 128000

    // ws layout: scnt[B*SLICES] | cy[B*SLICES*SEGCAP f32] | ci[same i32]
    const size_t n_scnt = (size_t)B * SLICES;
    const size_t n_seg  = (size_t)B * SLICES * SEGCAP;
    int*   scnt = (int*)d_ws;
    float* cy   = (float*)((char*)d_ws + n_scnt * 4);
    int*   ci   = (int*)((char*)d_ws + n_scnt * 4 + n_seg * 4);

    scan_kernel<<<B * SLICES, 256, 0, stream>>>(logits, V, scnt, cy, ci);
    select_kernel<<<B, 1024, 0, stream>>>(logits, u, topk, scnt, cy, ci, out, V);
}

// Round 11
// 101.989 us; speedup vs baseline: 1.0173x; 1.0173x over previous
//
#include <hip/hip_runtime.h>
#include <math.h>

// Sampler: temperature 0.8, top-k (k=50 input), top-p 0.9, inverse-CDF
// multinomial. B=128 rows, V=128000, fp32 logits -> int32 ids.
//
// R11: R10 scan (2048 blocks, interleaved, 8 named float4 MLP) + rebuilt
// select: after the rank sort, the whole tail (kth ties, softmax, top-p cut,
// renorm, vocab reorder, inverse-CDF) runs in WAVE 0 ONLY with zero
// __syncthreads -- shuffle butterflies/scans + ballots, 2 elements/lane
// (covers Kp <= 128; k=50 + ties fits trivially). One flag barrier picks
// fast (wave-0) vs the legacy full-block tail (only for Kp > 128 / M = 0;
// never fires on this data). Exact semantics preserved (absmax-0 lineage
// R1-R10; fp32 reassociation safe: decision margins >> rounding).
//  - scan: zero global atomics (R2 lesson), zero fences (R5 lesson).
//  - fallback (segment overflow / total < k): exact kth via binary search
//    on float key bits + rescan.

#define SLICES   16
#define SEGCAP   64
#define MSORT    1024

__device__ __forceinline__ unsigned fkey(float y) {
    unsigned b = __float_as_uint(y);
    return (b & 0x80000000u) ? ~b : (b | 0x80000000u);  // y asc -> key asc
}

// block-wide sum over 1024 threads; wpart = shared float[16]; ends synced
__device__ __forceinline__ float block_sum(float v, int tid, float* wpart) {
#pragma unroll
    for (int off = 32; off > 0; off >>= 1) v += __shfl_down(v, off, 64);
    if ((tid & 63) == 0) wpart[tid >> 6] = v;
    __syncthreads();
    if (tid < 64) {
        float s = (tid < 16) ? wpart[tid] : 0.0f;
#pragma unroll
        for (int off = 8; off > 0; off >>= 1) s += __shfl_down(s, off, 64);
        if (tid == 0) wpart[0] = s;
    }
    __syncthreads();
    float s = wpart[0];
    __syncthreads();
    return s;
}

// in-place block inclusive scan of arr[0..n), n <= 1024; ends synced
__device__ __forceinline__ void incl_scan(float* arr, int n, int tid, float* wpart) {
    float v = (tid < n) ? arr[tid] : 0.0f;
#pragma unroll
    for (int off = 1; off < 64; off <<= 1) {
        float o = __shfl_up(v, off, 64);
        if ((tid & 63) >= off) v += o;
    }
    if ((tid & 63) == 63) wpart[tid >> 6] = v;
    __syncthreads();
    if (tid < 64) {
        float w = (tid < 16) ? wpart[tid] : 0.0f;
#pragma unroll
        for (int off = 1; off < 16; off <<= 1) {
            float o = __shfl_up(w, off, 64);
            if (tid >= off) w += o;
        }
        if (tid < 16) wpart[tid] = w;
    }
    __syncthreads();
    const int wv = tid >> 6;
    const float base = (wv > 0) ? wpart[wv - 1] : 0.0f;
    if (tid < n) arr[tid] = v + base;
    __syncthreads();
}

// wave-wide (64-lane) helpers, no barriers
__device__ __forceinline__ float wsum(float v) {
#pragma unroll
    for (int off = 32; off > 0; off >>= 1) v += __shfl_xor(v, off, 64);
    return v;
}
__device__ __forceinline__ float wscan(float v, int lane) {
#pragma unroll
    for (int off = 1; off < 64; off <<= 1) {
        float o = __shfl_up(v, off, 64);
        if (lane >= off) v += o;
    }
    return v;
}

// ---------------- Kernel 1: interleaved full-device candidate scan ----------
__global__ __launch_bounds__(256)
void scan_kernel(const float* __restrict__ logits, int V,
                 int* __restrict__ scnt,
                 float* __restrict__ cy, int* __restrict__ ci)
{
    constexpr float YTH = 11.2f;   // x = 14.0
    __shared__ float lcy[SEGCAP];
    __shared__ int   lci[SEGCAP];
    __shared__ int   lcnt;

    const int tid = threadIdx.x;
    const int row = blockIdx.x / SLICES;
    const int sl  = blockIdx.x % SLICES;
    if (tid == 0) lcnt = 0;
    __syncthreads();

    const float* rowp = logits + (size_t)row * (size_t)V;
    const float4* rp4 = (const float4*)rowp;
    const int n4   = V >> 2;
    const int base = sl * 256 + tid;    // float4 index, stride 4096 per j

#define PUSH4(vv, i4)                                                            \
    {                                                                            \
        float _m = fmaxf(fmaxf((vv).x, (vv).y), fmaxf((vv).z, (vv).w));          \
        if (_m >= YTH) {                                                         \
            if ((vv).x >= YTH) { int _p = atomicAdd(&lcnt, 1);                   \
                if (_p < SEGCAP) { lcy[_p] = (vv).x; lci[_p] = (i4) * 4;     } } \
            if ((vv).y >= YTH) { int _p = atomicAdd(&lcnt, 1);                   \
                if (_p < SEGCAP) { lcy[_p] = (vv).y; lci[_p] = (i4) * 4 + 1; } } \
            if ((vv).z >= YTH) { int _p = atomicAdd(&lcnt, 1);                   \
                if (_p < SEGCAP) { lcy[_p] = (vv).z; lci[_p] = (i4) * 4 + 2; } } \
            if ((vv).w >= YTH) { int _p = atomicAdd(&lcnt, 1);                   \
                if (_p < SEGCAP) { lcy[_p] = (vv).w; lci[_p] = (i4) * 4 + 3; } } \
        }                                                                        \
    }

    if (sl * 256 + 255 + 7 * 4096 < n4) {
        // fast path: 8 unconditional back-to-back loads (full MLP)
        float4 a0 = rp4[base];
        float4 a1 = rp4[base + 4096];
        float4 a2 = rp4[base + 8192];
        float4 a3 = rp4[base + 12288];
        float4 a4 = rp4[base + 16384];
        float4 a5 = rp4[base + 20480];
        float4 a6 = rp4[base + 24576];
        float4 a7 = rp4[base + 28672];
        PUSH4(a0, base);
        PUSH4(a1, base + 4096);
        PUSH4(a2, base + 8192);
        PUSH4(a3, base + 12288);
        PUSH4(a4, base + 16384);
        PUSH4(a5, base + 20480);
        PUSH4(a6, base + 24576);
        PUSH4(a7, base + 28672);
    } else {
        // edge slices: clamped branch-free loads, validity-flagged pushes
        const int nc = n4 - 1;
        int i0 = base,          c0 = min(i0, nc);
        int i1 = base + 4096,   c1 = min(i1, nc);
        int i2 = base + 8192,   c2 = min(i2, nc);
        int i3 = base + 12288,  c3 = min(i3, nc);
        int i4_ = base + 16384, c4 = min(i4_, nc);
        int i5 = base + 20480,  c5 = min(i5, nc);
        int i6 = base + 24576,  c6 = min(i6, nc);
        int i7 = base + 28672,  c7 = min(i7, nc);
        float4 a0 = rp4[c0];
        float4 a1 = rp4[c1];
        float4 a2 = rp4[c2];
        float4 a3 = rp4[c3];
        float4 a4 = rp4[c4];
        float4 a5 = rp4[c5];
        float4 a6 = rp4[c6];
        float4 a7 = rp4[c7];
        if (i0 < n4) PUSH4(a0, i0);
        if (i1 < n4) PUSH4(a1, i1);
        if (i2 < n4) PUSH4(a2, i2);
        if (i3 < n4) PUSH4(a3, i3);
        if (i4_ < n4) PUSH4(a4, i4_);
        if (i5 < n4) PUSH4(a5, i5);
        if (i6 < n4) PUSH4(a6, i6);
        if (i7 < n4) PUSH4(a7, i7);
    }
    // general-V coverage beyond 32768 float4/row (empty for V=128000)
    for (int i = SLICES * 256 * 8 + sl * 256 + tid; i < n4; i += SLICES * 256) {
        float4 a = rp4[i];
        PUSH4(a, i);
    }
    if (sl == SLICES - 1) {   // scalar tail if V % 4 != 0
        for (int i = (n4 << 2) + tid; i < V; i += 256) {
            float y = rowp[i];
            if (y >= YTH) {
                int p = atomicAdd(&lcnt, 1);
                if (p < SEGCAP) { lcy[p] = y; lci[p] = i; }
            }
        }
    }
#undef PUSH4
    __syncthreads();

    const int cnt = lcnt;
    float* cyr = cy + ((size_t)row * SLICES + sl) * SEGCAP;
    int*   cir = ci + ((size_t)row * SLICES + sl) * SEGCAP;
    for (int p = tid; p < min(cnt, SEGCAP); p += 256) {
        cyr[p] = lcy[p];
        cir[p] = lci[p];
    }
    if (tid == 0) scnt[row * SLICES + sl] = cnt;  // cnt > SEGCAP => overflow
}

// ---------------- Kernel 2: per-row selection + sampling --------------------
__global__ __launch_bounds__(1024)
void select_kernel(const float* __restrict__ logits,
                   const float* __restrict__ uvec,
                   const int* __restrict__ topk_p,
                   const int* __restrict__ scnt,
                   const float* __restrict__ cy, const int* __restrict__ ci,
                   int* __restrict__ out, int V)
{
    constexpr float TEMP = 0.8f;
    constexpr float TOPP = 0.9f;
    constexpr float XTH2 = 16.0f;   // two-tier threshold in x-space

    __shared__ float gv[MSORT];
    __shared__ int   gi[MSORT];
    __shared__ float cv[MSORT];
    __shared__ int   cidx[MSORT];
    __shared__ float sq[MSORT];
    __shared__ float wpart[16];
    __shared__ float kth_sh;
    __shared__ int   segoff[SLICES + 1];
    __shared__ int   bad_sh, hi_cnt, cpos, scount, cnt_sh, M_sh, tie_cnt, L_cnt, ans_sh;
    __shared__ int   Kp_sh, fast_sh;

    const int tid  = threadIdx.x;
    const int lane = tid & 63;
    const int row  = blockIdx.x;
    const int nth  = blockDim.x;    // 1024
    const int k_in = *topk_p;

    const float* rowp = logits + (size_t)row * (size_t)V;

    if (tid == 0) { hi_cnt = 0; cpos = 0; scount = 0;
                    tie_cnt = 0; L_cnt = 0; ans_sh = V; }
    if (tid < 64) {
        int c = (tid < SLICES) ? scnt[row * SLICES + tid] : 0;
        int bad = (tid < SLICES) && (c > SEGCAP);
        int acc = min(c, SEGCAP);
#pragma unroll
        for (int off = 1; off < SLICES; off <<= 1) {
            int o = __shfl_up(acc, off, 64);
            if (tid >= off) acc += o;
        }
        if (tid < SLICES) segoff[tid + 1] = acc;
        if (tid == 0) segoff[0] = 0;
        unsigned long long bm = __ballot(bad);
        if (tid == 0) bad_sh = (bm != 0ULL);
    }
    __syncthreads();

    const int M_all = segoff[SLICES];
    int M;
    if (!bad_sh && M_all >= k_in && M_all <= MSORT) {
        {
            const int s = tid >> 6;         // one wave per segment
            const int off = segoff[s];
            const int c   = segoff[s + 1] - off;
            if (lane < c) {
                const size_t base = ((size_t)row * SLICES + s) * SEGCAP + lane;
                gv[off + lane] = cy[base] / TEMP;
                gi[off + lane] = ci[base];
            }
        }
        __syncthreads();
        {
            bool pred = (tid < M_all) && (gv[tid] >= XTH2);
            unsigned long long bm = __ballot(pred);
            if (lane == 0 && bm) atomicAdd(&hi_cnt, (int)__popcll(bm));
        }
        __syncthreads();
        const float thr = (hi_cnt >= k_in) ? XTH2 : -1e38f;
        {
            bool pred = (tid < M_all) && (gv[tid] >= thr);
            unsigned long long bm = __ballot(pred);
            if (bm) {
                int fl = (int)__ffsll(bm) - 1;
                int bs = 0;
                if (pred && lane == fl) bs = atomicAdd(&cpos, (int)__popcll(bm));
                bs = __shfl(bs, fl, 64);
                if (pred) {
                    int p = bs + (int)__popcll(bm & ((1ULL << lane) - 1ULL));
                    cv[p] = gv[tid]; cidx[p] = gi[tid];
                }
            }
        }
        __syncthreads();
        M = cpos;
    } else {
        // exact fallback: kth value via binary search on float key bits
        unsigned lo = 0;
        for (int bit = 31; bit >= 0; --bit) {
            unsigned t = lo | (1u << bit);
            int local = 0;
            for (int i = tid; i < V; i += nth) local += (fkey(rowp[i]) >= t);
            if (tid == 0) cnt_sh = 0;
            __syncthreads();
            atomicAdd(&cnt_sh, local);
            __syncthreads();
            if (cnt_sh >= k_in) lo = t;
            __syncthreads();
        }
        for (int i = tid; i < V; i += nth) {
            float y = rowp[i];
            if (fkey(y) >= lo) {
                int p = atomicAdd(&scount, 1);
                if (p < MSORT) { cv[p] = y / TEMP; cidx[p] = i; }
            }
        }
        __syncthreads();
        M = min(scount, MSORT);
    }
    if (tid == 0) M_sh = M;
    __syncthreads();
    M = M_sh;

    // pad to multiple of 4 with sentinels (branch-free unrolled inner loop)
    const int Mpad = (M + 3) & ~3;
    for (int t = M + tid; t < Mpad; t += nth) { cv[t] = -1e38f; cidx[t] = 0x7fffffff; }
    __syncthreads();

    // rank sort: x desc, tie idx asc (== argsort(-x)); writes into gv/gi
    for (int t = tid; t < M; t += nth) {
        const float v = cv[t]; const int ix = cidx[t];
        int r = 0;
        for (int j = 0; j < Mpad; j += 4) {
            float v0 = cv[j],     v1 = cv[j + 1];
            float v2 = cv[j + 2], v3 = cv[j + 3];
            int   i0 = cidx[j],     i1 = cidx[j + 1];
            int   i2 = cidx[j + 2], i3 = cidx[j + 3];
            r += (v0 > v || (v0 == v && i0 < ix));
            r += (v1 > v || (v1 == v && i1 < ix));
            r += (v2 > v || (v2 == v && i2 < ix));
            r += (v3 > v || (v3 == v && i3 < ix));
        }
        gv[r] = v; gi[r] = ix;
    }
    __syncthreads();

    // ---- decide fast (wave-0, Kp <= 128) vs slow tail ----
    if (tid < 64) {
        int kk = (M > 0) ? min(max(k_in, 1), M) : 0;
        float kth = (M > 0) ? gv[kk - 1] : 0.0f;
        int j0 = min(kk + lane, MSORT - 1);
        int j1 = min(kk + 64 + lane, MSORT - 1);
        bool t0 = (M > 0) && (kk + lane < M)      && (gv[j0] == kth);
        bool t1 = (M > 0) && (kk + 64 + lane < M) && (gv[j1] == kth);
        int cnt = (int)__popcll(__ballot(t0)) + (int)__popcll(__ballot(t1));
        if (lane == 0) {
            int Kp = kk + cnt;
            Kp_sh = Kp;
            fast_sh = (M > 0) && (Kp <= 128);
        }
    }
    __syncthreads();

    if (fast_sh) {
        // ================= wave-0 barrier-free tail =================
        if (tid < 64) {
            const int Kp = Kp_sh;
            const int e0 = lane, e1 = lane + 64;
            const float mm = gv[0];
            float se0 = (e0 < Kp) ? expf(gv[e0] - mm) : 0.0f;
            float se1 = (e1 < Kp) ? expf(gv[e1] - mm) : 0.0f;

            const float sum1 = wsum(se0 + se1);
            float q0 = se0 / sum1, q1 = se1 / sum1;

            // inclusive cdf over element order [0..Kp)
            float s0 = wscan(q0, lane);
            float T0 = __shfl(s0, 63, 64);
            float s1 = wscan(q1, lane) + T0;

            float prev0 = __shfl_up(s0, 1, 64);                 // Q[e0-1], lane0 unused
            float prev1 = __shfl_up(s1, 1, 64);
            if (lane == 0) prev1 = T0;                          // Q[63]
            bool c0 = (e0 >= 1) && (e0 < Kp) && (prev0 <= TOPP);
            bool c1 = (e1 < Kp) && (prev1 <= TOPP);
            const int L = 1 + (int)__popcll(__ballot(c0)) + (int)__popcll(__ballot(c1));

            const float sum2 = wsum(((e0 < L) ? se0 : 0.0f) + ((e1 < L) ? se1 : 0.0f));
            float p0 = se0 / sum2, p1 = se1 / sum2;
            int i0 = (e0 < L) ? gi[e0] : 0x7fffffff;
            int i1 = (e1 < L) ? gi[e1] : 0x7fffffff;

            // pad gi[L..Lpad) with INT_MAX for the x4-unrolled rank loop
            const int Lpad = (L + 3) & ~3;
            if (lane < Lpad - L) gi[L + lane] = 0x7fffffff;
            __builtin_amdgcn_wave_barrier();

            int r0 = 0, r1 = 0;
            for (int j = 0; j < Lpad; j += 4) {
                int g0 = gi[j], g1 = gi[j + 1], g2 = gi[j + 2], g3 = gi[j + 3];
                r0 += (g0 < i0) + (g1 < i0) + (g2 < i0) + (g3 < i0);
                r1 += (g0 < i1) + (g1 < i1) + (g2 < i1) + (g3 < i1);
            }
            if (e0 < L) { sq[r0] = p0; cidx[r0] = i0; }
            if (e1 < L) { sq[r1] = p1; cidx[r1] = i1; }
            __builtin_amdgcn_wave_barrier();

            // vocab-order cdf + unique crossing
            float g0v = (e0 < L) ? sq[e0] : 0.0f;
            float g1v = (e1 < L) ? sq[e1] : 0.0f;
            int   vi0 = (e0 < L) ? cidx[e0] : 0;
            int   vi1 = (e1 < L) ? cidx[e1] : 0;
            float C0 = wscan(g0v, lane);
            float TT = __shfl(C0, 63, 64);
            float C1 = wscan(g1v, lane) + TT;
            float pc0 = __shfl_up(C0, 1, 64);
            float pc1 = __shfl_up(C1, 1, 64);
            if (lane == 0) pc1 = TT;
            const float uu = uvec[row];
            bool f0 = (e0 < L) && (C0 > uu) && (e0 == 0 || pc0 <= uu);
            bool f1 = (e1 < L) && (C1 > uu) && (pc1 <= uu);
            int ans = V;
            if (f0) ans = vi0;
            if (f1) ans = vi1;
#pragma unroll
            for (int off = 32; off > 0; off >>= 1)
                ans = min(ans, __shfl_xor(ans, off, 64));
            if (lane == 0) out[row] = ans;
        }
        return;   // block-uniform
    }

    // ================= slow full-block tail (Kp > 128 / M == 0) =============
    const int kk = (M > 0) ? min(max(k_in, 1), M) : 0;
    const float mm = (M > 0) ? gv[0] : 0.0f;
    if (tid < M) cv[tid] = expf(gv[tid] - mm);
    if (tid == 0 && M > 0) kth_sh = gv[kk - 1];
    __syncthreads();

    {
        bool f = (M > 0) && (tid >= kk) && (tid < M) && (gv[tid] == kth_sh);
        unsigned long long bm = __ballot(f);
        if (lane == 0 && bm) atomicAdd(&tie_cnt, (int)__popcll(bm));
    }
    __syncthreads();
    const int Kp = kk + tie_cnt;

    const float sum1 = block_sum((tid < Kp) ? cv[tid] : 0.0f, tid, wpart);

    if (tid < Kp) sq[tid] = cv[tid] / sum1;
    incl_scan(sq, Kp, tid, wpart);
    {
        bool f = (tid >= 1) && (tid < Kp) && (sq[tid - 1] <= TOPP);
        unsigned long long bm = __ballot(f);
        if (lane == 0 && bm) atomicAdd(&L_cnt, (int)__popcll(bm));
    }
    __syncthreads();
    const int L = (M > 0) ? (1 + L_cnt) : 0;

    const float sum2 = block_sum((tid < L) ? cv[tid] : 0.0f, tid, wpart);

    if (tid < L) {
        const int ix = gi[tid];
        int r = 0;
        for (int j = 0; j < L; ++j) r += (gi[j] < ix);
        sq[r] = cv[tid] / sum2;
        cidx[r] = ix;
    }
    __syncthreads();

    incl_scan(sq, L, tid, wpart);
    {
        const float uu = uvec[row];
        bool f = (tid < L) && (sq[tid] > uu) && (tid == 0 || sq[tid - 1] <= uu);
        if (f) ans_sh = cidx[tid];
    }
    __syncthreads();
    if (tid == 0) out[row] = ans_sh;
}

extern "C" void kernel_launch(void* const* d_in, const int* in_sizes, int n_in,
                              void* d_out, int out_size, void* d_ws, size_t ws_size,
                              hipStream_t stream) {
    const float* logits = (const float*)d_in[0];
    const float* u      = (const float*)d_in[1];
    const int*   topk   = (const int*)d_in[2];
    int*         out    = (int*)d_out;

    const int B = out_size;              // 128 rows
    const int V = in_sizes[0] / B;       // 128000

    // ws layout: scnt[B*SLICES] | cy[B*SLICES*SEGCAP f32] | ci[same i32]
    const size_t n_scnt = (size_t)B * SLICES;
    const size_t n_seg  = (size_t)B * SLICES * SEGCAP;
    int*   scnt = (int*)d_ws;
    float* cy   = (float*)((char*)d_ws + n_scnt * 4);
    int*   ci   = (int*)((char*)d_ws + n_scnt * 4 + n_seg * 4);

    scan_kernel<<<B * SLICES, 256, 0, stream>>>(logits, V, scnt, cy, ci);
    select_kernel<<<B, 1024, 0, stream>>>(logits, u, topk, scnt, cy, ci, out, V);
}